// Round 1
// baseline (1154.961 us; speedup 1.0000x reference)
//
#include <hip/hip_runtime.h>

typedef __attribute__((ext_vector_type(8))) short short8;
typedef __attribute__((ext_vector_type(4))) float f32x4;

// Problem constants: x[B=8][C_in=64][T=1024][F=256], weight[G=32][U=8][64][64],
// bias[64][1][256], out[8][64][1024][256].  W_f[i][o] = weight[f*4096 + i*64 + o].

__device__ __forceinline__ unsigned short f2bf(float f) {
    unsigned int u = __builtin_bit_cast(unsigned int, f);
    return (unsigned short)((u + 0x8000u) >> 16);   // round-half-up to bf16
}

// ---------------------------------------------------------------------------
// Pre-pass: weight fp32 [f][i][o]  ->  wt bf16 [f][o][i]  (i contiguous so the
// MFMA B-fragment is one 16B load).  One block per f; LDS transpose, padded
// +1 to kill bank conflicts.  2 MB output, L2-resident during the main kernel.
// ---------------------------------------------------------------------------
__global__ void wt_transform(const float* __restrict__ w,
                             unsigned short* __restrict__ wt) {
    __shared__ float sw[64 * 65];
    const int f = blockIdx.x;
    const float* wf = w + f * 4096;
#pragma unroll
    for (int r = 0; r < 16; ++r) {
        int idx = r * 256 + threadIdx.x;      // coalesced read, o fastest
        int i = idx >> 6, o = idx & 63;
        sw[i * 65 + o] = wf[idx];
    }
    __syncthreads();
    unsigned short* wtf = wt + f * 4096;
#pragma unroll
    for (int r = 0; r < 16; ++r) {
        int idx = r * 256 + threadIdx.x;      // coalesced write, i fastest
        int o = idx >> 6, i = idx & 63;
        wtf[o * 64 + i] = f2bf(sw[i * 65 + o]);
    }
}

// ---------------------------------------------------------------------------
// Main kernel.  Block = 256 threads = 4 waves; tile = (b, 16 t, 16 f).
// Wave w owns f_loc in [4w, 4w+4): it stages that slice of x into LDS (bf16,
// [f][t][i] with 16B-block swizzle blk^=(t&7)) and computes it.  Waves never
// share LDS data -> no __syncthreads needed.
// MFMA 16x16x32 bf16: M=t(16), N=o(16), K=i(2 steps of 32).
// Epilogue: float4 stores across the 4 f-accumulators (f-contiguous, 16B).
// ---------------------------------------------------------------------------
__global__ __launch_bounds__(256, 4) void gl_kernel(
        const float* __restrict__ x, const unsigned short* __restrict__ wt,
        const float* __restrict__ bias, float* __restrict__ y) {
    // 16 f * 16 t * 64 i bf16 = 32 KB
    __shared__ unsigned short xs[16 * 1024];

    // Block swizzle: blk = (bt<<4) | (fcl<<3) | fch.
    // XCD = blk&7 = fch -> XCD k owns f in [32k, 32k+32) (full 128B lines);
    // the two half-line blocks (fcl=0/1) are dispatch-adjacent on the same XCD.
    const int blk = blockIdx.x;
    const int fch = blk & 7;
    const int fcl = (blk >> 3) & 1;
    const int bt  = blk >> 4;            // 0..511
    const int bb  = bt >> 6;             // batch 0..7
    const int tt  = bt & 63;             // t-chunk 0..63
    const int f0  = fch * 32 + fcl * 16;
    const int t0  = tt * 16;

    const int tid  = threadIdx.x;
    const int w    = tid >> 6;           // wave id -> f_loc base 4w
    const int lane = tid & 63;
    const int t_s  = lane & 15;          // staging t
    const int i2   = (lane >> 4) & 3;    // staging i low bits

    // ---- stage x[b, :, t0:t0+16, f0+4w : f0+4w+4] -> LDS (bf16, swizzled) ----
    const float* xg = x + ((size_t)(bb * 64) * 1024 + (t0 + t_s)) * 256 + f0 + 4 * w;
    unsigned short* xsw = xs + (4 * w) * 1024 + t_s * 64;
    const int tmask = t_s & 7;
#pragma unroll
    for (int ihi = 0; ihi < 16; ++ihi) {
        const int i = ihi * 4 + i2;
        f32x4 v = *(const f32x4*)(xg + (size_t)i * (1024 * 256));
        const int ip = (((i >> 3) ^ tmask) * 8) + (i & 7);
        unsigned short* p = xsw + ip;
        p[0 * 1024] = f2bf(v[0]);
        p[1 * 1024] = f2bf(v[1]);
        p[2 * 1024] = f2bf(v[2]);
        p[3 * 1024] = f2bf(v[3]);
    }
    // No barrier: this wave reads only its own slice; LDS ops are in-order
    // per wave and the compiler inserts lgkmcnt waits on the RAW dependence.

    // ---- A fragments: A[m=lane&15][k=(lane>>4)*8+j] = x[t0+m][i=k1*32+k] ----
    const int tl = lane & 15;            // m for A/D, n (o_local) for B/D
    const int q  = lane >> 4;
    const unsigned short* xr = xs + 4 * w * 1024 + tl * 64;
    const int tm = tl & 7;
    short8 A[4][2];
#pragma unroll
    for (int fi = 0; fi < 4; ++fi)
#pragma unroll
        for (int k1 = 0; k1 < 2; ++k1)
            A[fi][k1] = *(const short8*)(xr + fi * 1024 + (((k1 * 4 + q) ^ tm) * 8));

    const unsigned short* wtb = wt + (size_t)(f0 + 4 * w) * 4096 + q * 8;
    float* yb = y + ((size_t)(bb * 64) * 1024 + t0 + q * 4) * 256 + f0 + 4 * w;

#pragma unroll
    for (int n = 0; n < 4; ++n) {
        const int o = n * 16 + tl;
        const unsigned short* wo = wtb + o * 64;
        f32x4 acc[4];
#pragma unroll
        for (int fi = 0; fi < 4; ++fi) {
            short8 B0 = *(const short8*)(wo + fi * 4096);
            short8 B1 = *(const short8*)(wo + fi * 4096 + 32);
            f32x4 z = {0.f, 0.f, 0.f, 0.f};
            acc[fi] = __builtin_amdgcn_mfma_f32_16x16x32_bf16(A[fi][0], B0, z, 0, 0, 0);
            acc[fi] = __builtin_amdgcn_mfma_f32_16x16x32_bf16(A[fi][1], B1, acc[fi], 0, 0, 0);
        }
        // bias[o][0][f0+4w .. +3], 16B aligned
        f32x4 bs = *(const f32x4*)(bias + o * 256 + f0 + 4 * w);
        float* yo = yb + (size_t)o * (1024 * 256);
#pragma unroll
        for (int r = 0; r < 4; ++r) {
            // D layout: col(o)=lane&15, row(t)=q*4+r; 4 f-accumulators -> float4
            f32x4 out;
            out[0] = acc[0][r] + bs[0];
            out[1] = acc[1][r] + bs[1];
            out[2] = acc[2][r] + bs[2];
            out[3] = acc[3][r] + bs[3];
            *(f32x4*)(yo + (size_t)r * 256) = out;
        }
    }
}

extern "C" void kernel_launch(void* const* d_in, const int* in_sizes, int n_in,
                              void* d_out, int out_size, void* d_ws, size_t ws_size,
                              hipStream_t stream) {
    const float* x    = (const float*)d_in[0];
    const float* wgt  = (const float*)d_in[1];
    const float* bias = (const float*)d_in[2];
    float* out = (float*)d_out;
    unsigned short* wt = (unsigned short*)d_ws;   // 256*4096*2 = 2 MB scratch

    wt_transform<<<256, 256, 0, stream>>>(wgt, wt);
    // grid: 512 (b,t) chunks * 2 half-lines * 8 XCD f-chunks = 8192 blocks
    gl_kernel<<<8192, 256, 0, stream>>>(x, wt, bias, out);
}